// Round 1
// baseline (378.258 us; speedup 1.0000x reference)
//
#include <hip/hip_runtime.h>

#define DMODEL 1024
#define NHEAD  16
#define HWID   64
#define FFDIM  4096
#define NBATCH 2
#define SEQT   2048
#define NTOK   4096   // NBATCH*SEQT

using bf8   = __attribute__((ext_vector_type(8))) short;
using f32x4 = __attribute__((ext_vector_type(4))) float;

__device__ inline short to_bf16(float f) {
  unsigned u = __float_as_uint(f);
  return (short)((u + 0x7fffu + ((u >> 16) & 1u)) >> 16);
}
__device__ inline float from_bf16(short s) {
  return __uint_as_float(((unsigned)(unsigned short)s) << 16);
}

__device__ inline void lds_load16(const void* g, void* l) {
  __builtin_amdgcn_global_load_lds(
      (const __attribute__((address_space(1))) void*)g,
      (__attribute__((address_space(3))) void*)l, 16, 0, 0);
}

// ---------------- f32 -> bf16 convert (weights) ----------------
__global__ __launch_bounds__(256)
void cvt_kernel(const float* __restrict__ in, short* __restrict__ out, int n4) {
  int i = blockIdx.x * 256 + threadIdx.x;
  if (i < n4) {
    float4 v = ((const float4*)in)[i];
    short4 o;
    o.x = to_bf16(v.x); o.y = to_bf16(v.y);
    o.z = to_bf16(v.z); o.w = to_bf16(v.w);
    ((short4*)out)[i] = o;
  }
}

// ---------------- LayerNorm (f32 in -> bf16 out) ----------------
__global__ __launch_bounds__(256)
void ln_kernel(const float* __restrict__ x, const float* __restrict__ g,
               const float* __restrict__ b, short* __restrict__ out) {
  const int row = blockIdx.x;
  const int t = threadIdx.x;
  const float4 v = ((const float4*)(x + (long)row * DMODEL))[t];
  float s  = v.x + v.y + v.z + v.w;
  float s2 = v.x * v.x + v.y * v.y + v.z * v.z + v.w * v.w;
#pragma unroll
  for (int m = 1; m < 64; m <<= 1) {
    s  += __shfl_xor(s, m);
    s2 += __shfl_xor(s2, m);
  }
  __shared__ float red[8];
  if ((t & 63) == 0) { red[t >> 6] = s; red[4 + (t >> 6)] = s2; }
  __syncthreads();
  s  = red[0] + red[1] + red[2] + red[3];
  s2 = red[4] + red[5] + red[6] + red[7];
  const float mu = s * (1.f / DMODEL);
  const float rs = rsqrtf(s2 * (1.f / DMODEL) - mu * mu + 1e-5f);
  const float4 gv = ((const float4*)g)[t];
  const float4 bv = ((const float4*)b)[t];
  short4 o;
  o.x = to_bf16((v.x - mu) * rs * gv.x + bv.x);
  o.y = to_bf16((v.y - mu) * rs * gv.y + bv.y);
  o.z = to_bf16((v.z - mu) * rs * gv.z + bv.z);
  o.w = to_bf16((v.w - mu) * rs * gv.w + bv.w);
  ((short4*)(out + (long)row * DMODEL))[t] = o;
}

// ---------------- NT GEMM: C[M][N] = A[M][K] * Bw[N][K]^T ----------------
// EPI 0: bf16 store; 1: SiLU + bf16 store; 2: f32 store of resid + C
template <int EPI>
__global__ __launch_bounds__(256)
void gemm_nt(const short* __restrict__ A, const short* __restrict__ Bw,
             void* __restrict__ Cout, const float* __restrict__ resid,
             int M, int N, int K) {
  __shared__ short As[128 * 32];
  __shared__ short Bs[128 * 32];
  const int tid = threadIdx.x;
  const int w = tid >> 6, lane = tid & 63;
  const int l15 = lane & 15, l4 = lane >> 4;
  const long bm = (long)blockIdx.y * 128, bn = (long)blockIdx.x * 128;
  const int wr = (w >> 1) * 64, wc = (w & 1) * 64;
  f32x4 acc[4][4] = {};
  for (int k0 = 0; k0 < K; k0 += 32) {
    __syncthreads();
#pragma unroll
    for (int i = 0; i < 2; ++i) {
      const int chunk = (i * 4 + w) * 1024;       // byte base of wave chunk
      const int o = chunk + lane * 16;            // this lane's dest byte
      const int row = o >> 6, colb = o & 63;      // 64B per 32-elem bf16 row
      lds_load16(A  + (bm + row) * (long)K + k0 + (colb >> 1), (char*)As + chunk);
      lds_load16(Bw + (bn + row) * (long)K + k0 + (colb >> 1), (char*)Bs + chunk);
    }
    __syncthreads();
    bf8 af[4], bfr[4];
#pragma unroll
    for (int m = 0; m < 4; ++m)
      af[m] = *(const bf8*)&As[(wr + m * 16 + l15) * 32 + l4 * 8];
#pragma unroll
    for (int n = 0; n < 4; ++n)
      bfr[n] = *(const bf8*)&Bs[(wc + n * 16 + l15) * 32 + l4 * 8];
#pragma unroll
    for (int m = 0; m < 4; ++m)
#pragma unroll
      for (int n = 0; n < 4; ++n)
        acc[m][n] = __builtin_amdgcn_mfma_f32_16x16x32_bf16(af[m], bfr[n], acc[m][n], 0, 0, 0);
  }
#pragma unroll
  for (int m = 0; m < 4; ++m) {
#pragma unroll
    for (int n = 0; n < 4; ++n) {
      const long col = bn + wc + n * 16 + l15;
#pragma unroll
      for (int r = 0; r < 4; ++r) {
        const long row = bm + wr + m * 16 + l4 * 4 + r;
        float v = acc[m][n][r];
        if (EPI == 0) {
          ((short*)Cout)[row * N + col] = to_bf16(v);
        } else if (EPI == 1) {
          ((short*)Cout)[row * N + col] = to_bf16(v / (1.f + __expf(-v)));
        } else {
          ((float*)Cout)[row * N + col] = resid[row * N + col] + v;
        }
      }
    }
  }
}

// ---------------- Flash attention w/ ALiBi + causal ----------------
// grid: (T/64 q-tiles, NBATCH*NHEAD); 256 thr = 4 waves * 16 q-rows
__global__ __launch_bounds__(256)
void attn_kernel(const short* __restrict__ qg, const short* __restrict__ kg,
                 const short* __restrict__ vtg, const short* __restrict__ xn,
                 float* __restrict__ att) {
  const int bh = blockIdx.y, b = bh >> 4, h = bh & 15;
  const int qb = blockIdx.x * 64;
  const int tid = threadIdx.x, w = tid >> 6, lane = tid & 63;
  const int l15 = lane & 15, l4 = lane >> 4;
  __shared__ short Ks[64][72];
  __shared__ short Vs[64][72];
  __shared__ short Ps[4][16][72];

  bf8 qf[2];
  {
    const long qrow = ((long)(b * SEQT + qb + w * 16 + l15)) * DMODEL + h * HWID;
    qf[0] = *(const bf8*)&qg[qrow + l4 * 8];
    qf[1] = *(const bf8*)&qg[qrow + 32 + l4 * 8];
  }
  const float slope = exp2f(-0.5f * (float)(h + 1));
  float m_run[4] = {-1e30f, -1e30f, -1e30f, -1e30f};
  float l_run[4] = {0.f, 0.f, 0.f, 0.f};
  f32x4 acc_o[4] = {};
  const int row0 = qb + w * 16 + l4 * 4;   // + r gives absolute q row (in T)
  const int ntile = qb / 64 + 1;

  for (int kt = 0; kt < ntile; ++kt) {
    __syncthreads();
#pragma unroll
    for (int i = 0; i < 2; ++i) {
      const int idx = tid + i * 256;           // 0..511
      const int r = idx >> 3, c = idx & 7;
      *(bf8*)&Ks[r][c * 8] =
          *(const bf8*)&kg[((long)(b * SEQT + kt * 64 + r)) * DMODEL + h * HWID + c * 8];
      *(bf8*)&Vs[r][c * 8] =
          *(const bf8*)&vtg[((long)(h * HWID + r)) * NTOK + b * SEQT + kt * 64 + c * 8];
    }
    __syncthreads();

    f32x4 sacc[4] = {};
#pragma unroll
    for (int n = 0; n < 4; ++n) {
      bf8 kf0 = *(const bf8*)&Ks[n * 16 + l15][l4 * 8];
      bf8 kf1 = *(const bf8*)&Ks[n * 16 + l15][32 + l4 * 8];
      sacc[n] = __builtin_amdgcn_mfma_f32_16x16x32_bf16(qf[0], kf0, sacc[n], 0, 0, 0);
      sacc[n] = __builtin_amdgcn_mfma_f32_16x16x32_bf16(qf[1], kf1, sacc[n], 0, 0, 0);
    }

    float pv[4][4], pmax[4] = {-1e30f, -1e30f, -1e30f, -1e30f};
#pragma unroll
    for (int n = 0; n < 4; ++n) {
      const int col = kt * 64 + n * 16 + l15;
#pragma unroll
      for (int r = 0; r < 4; ++r) {
        float s = sacc[n][r] * 0.125f + slope * (float)(col - (row0 + r));
        if (col > row0 + r) s = -1e30f;
        pv[n][r] = s;
        pmax[r] = fmaxf(pmax[r], s);
      }
    }
#pragma unroll
    for (int r = 0; r < 4; ++r) {
#pragma unroll
      for (int m = 1; m < 16; m <<= 1) pmax[r] = fmaxf(pmax[r], __shfl_xor(pmax[r], m));
      const float nm = fmaxf(m_run[r], pmax[r]);
      const float alpha = __expf(m_run[r] - nm);
      m_run[r] = nm;
      l_run[r] *= alpha;
#pragma unroll
      for (int d = 0; d < 4; ++d) acc_o[d][r] *= alpha;
    }
    float rsum[4] = {0.f, 0.f, 0.f, 0.f};
#pragma unroll
    for (int n = 0; n < 4; ++n)
#pragma unroll
      for (int r = 0; r < 4; ++r) {
        const float p = __expf(pv[n][r] - m_run[r]);
        pv[n][r] = p;
        rsum[r] += p;
      }
#pragma unroll
    for (int r = 0; r < 4; ++r) {
#pragma unroll
      for (int m = 1; m < 16; m <<= 1) rsum[r] += __shfl_xor(rsum[r], m);
      l_run[r] += rsum[r];
    }
#pragma unroll
    for (int n = 0; n < 4; ++n)
#pragma unroll
      for (int r = 0; r < 4; ++r)
        Ps[w][l4 * 4 + r][n * 16 + l15] = to_bf16(pv[n][r]);

    bf8 pf0 = *(const bf8*)&Ps[w][l15][l4 * 8];
    bf8 pf1 = *(const bf8*)&Ps[w][l15][32 + l4 * 8];
#pragma unroll
    for (int d = 0; d < 4; ++d) {
      bf8 vf0 = *(const bf8*)&Vs[d * 16 + l15][l4 * 8];
      bf8 vf1 = *(const bf8*)&Vs[d * 16 + l15][32 + l4 * 8];
      acc_o[d] = __builtin_amdgcn_mfma_f32_16x16x32_bf16(pf0, vf0, acc_o[d], 0, 0, 0);
      acc_o[d] = __builtin_amdgcn_mfma_f32_16x16x32_bf16(pf1, vf1, acc_o[d], 0, 0, 0);
    }
  }

#pragma unroll
  for (int d = 0; d < 4; ++d)
#pragma unroll
    for (int r = 0; r < 4; ++r) {
      const long idx =
          ((long)(b * SEQT + qb + w * 16 + l4 * 4 + r)) * DMODEL + h * HWID + d * 16 + l15;
      att[idx] = from_bf16(xn[idx]) + acc_o[d][r] / l_run[r];
    }
}

// ---------------- launcher ----------------
extern "C" void kernel_launch(void* const* d_in, const int* in_sizes, int n_in,
                              void* d_out, int out_size, void* d_ws, size_t ws_size,
                              hipStream_t stream) {
  (void)in_sizes; (void)n_in; (void)out_size; (void)ws_size;
  const float* x  = (const float*)d_in[0];
  const float* Wq = (const float*)d_in[1];
  const float* Wk = (const float*)d_in[2];
  const float* Wv = (const float*)d_in[3];
  const float* W1 = (const float*)d_in[4];
  const float* W2 = (const float*)d_in[5];
  const float* g1 = (const float*)d_in[6];
  const float* b1 = (const float*)d_in[7];
  const float* g2 = (const float*)d_in[8];
  const float* b2 = (const float*)d_in[9];

  char* ws = (char*)d_ws;
  const size_t MB = 1024 * 1024;
  short* xn   = (short*)(ws + 0);        // 8 MB  [NTOK][D]
  short* qb_  = (short*)(ws + 8  * MB);  // 8 MB  [NTOK][D]
  short* kb_  = (short*)(ws + 16 * MB);  // 8 MB  [NTOK][D]
  short* vT   = (short*)(ws + 24 * MB);  // 8 MB  [D][NTOK]
  float* att  = (float*)(ws + 32 * MB);  // 16 MB [NTOK][D]
  short* hb   = (short*)(ws + 48 * MB);  // 8 MB  [NTOK][D]
  short* wq_b = (short*)(ws + 56 * MB);  // 2 MB
  short* wk_b = (short*)(ws + 58 * MB);  // 2 MB
  short* wv_b = (short*)(ws + 60 * MB);  // 2 MB
  short* w1_b = (short*)(ws + 62 * MB);  // 8 MB
  short* w2_b = (short*)(ws + 70 * MB);  // 8 MB
  short* m1   = (short*)(ws + 0);        // 32 MB [NTOK][FF] (aliases xn/q/k/vT, dead by then)

  cvt_kernel<<<1024, 256, 0, stream>>>(Wq, wq_b, 262144);
  cvt_kernel<<<1024, 256, 0, stream>>>(Wk, wk_b, 262144);
  cvt_kernel<<<1024, 256, 0, stream>>>(Wv, wv_b, 262144);
  cvt_kernel<<<4096, 256, 0, stream>>>(W1, w1_b, 1048576);
  cvt_kernel<<<4096, 256, 0, stream>>>(W2, w2_b, 1048576);

  ln_kernel<<<NTOK, 256, 0, stream>>>(x, g1, b1, xn);

  gemm_nt<0><<<dim3(8, 32), 256, 0, stream>>>(xn, wq_b, qb_, nullptr, NTOK, DMODEL, DMODEL);
  gemm_nt<0><<<dim3(8, 32), 256, 0, stream>>>(xn, wk_b, kb_, nullptr, NTOK, DMODEL, DMODEL);
  gemm_nt<0><<<dim3(32, 8), 256, 0, stream>>>(wv_b, xn, vT, nullptr, DMODEL, NTOK, DMODEL);

  attn_kernel<<<dim3(32, 32), 256, 0, stream>>>(qb_, kb_, vT, xn, att);

  ln_kernel<<<NTOK, 256, 0, stream>>>(att, g2, b2, hb);

  gemm_nt<1><<<dim3(32, 32), 256, 0, stream>>>(hb, w1_b, m1, nullptr, NTOK, FFDIM, DMODEL);
  gemm_nt<2><<<dim3(8, 32), 256, 0, stream>>>(m1, w2_b, d_out, att, NTOK, DMODEL, FFDIM);
}

// Round 2
// 306.591 us; speedup vs baseline: 1.2338x; 1.2338x over previous
//
#include <hip/hip_runtime.h>

#define DMODEL 1024
#define NHEAD  16
#define HWID   64
#define FFDIM  4096
#define NBATCH 2
#define SEQT   2048
#define NTOK   4096   // NBATCH*SEQT

using bf8    = __attribute__((ext_vector_type(8))) short;
using f32x4  = __attribute__((ext_vector_type(4))) float;
using f32x16 = __attribute__((ext_vector_type(16))) float;

__device__ inline short to_bf16(float f) {
  unsigned u = __float_as_uint(f);
  return (short)((u + 0x7fffu + ((u >> 16) & 1u)) >> 16);
}
__device__ inline float from_bf16(short s) {
  return __uint_as_float(((unsigned)(unsigned short)s) << 16);
}
__device__ inline float exp2_fast(float x) {
  float r;
  asm("v_exp_f32 %0, %1" : "=v"(r) : "v"(x));
  return r;
}
__device__ inline unsigned cvt_pk_bf16(float lo, float hi) {
  unsigned r;
  asm("v_cvt_pk_bf16_f32 %0, %1, %2" : "=v"(r) : "v"(lo), "v"(hi));
  return r;
}

__device__ inline void lds_load16(const void* g, void* l) {
  __builtin_amdgcn_global_load_lds(
      (const __attribute__((address_space(1))) void*)g,
      (__attribute__((address_space(3))) void*)l, 16, 0, 0);
}

// ---------------- f32 -> bf16 convert (weights) ----------------
__global__ __launch_bounds__(256)
void cvt_kernel(const float* __restrict__ in, short* __restrict__ out, int n4) {
  int i = blockIdx.x * 256 + threadIdx.x;
  if (i < n4) {
    float4 v = ((const float4*)in)[i];
    short4 o;
    o.x = to_bf16(v.x); o.y = to_bf16(v.y);
    o.z = to_bf16(v.z); o.w = to_bf16(v.w);
    ((short4*)out)[i] = o;
  }
}

// ---------------- LayerNorm (f32 in -> bf16 out) ----------------
__global__ __launch_bounds__(256)
void ln_kernel(const float* __restrict__ x, const float* __restrict__ g,
               const float* __restrict__ b, short* __restrict__ out) {
  const int row = blockIdx.x;
  const int t = threadIdx.x;
  const float4 v = ((const float4*)(x + (long)row * DMODEL))[t];
  float s  = v.x + v.y + v.z + v.w;
  float s2 = v.x * v.x + v.y * v.y + v.z * v.z + v.w * v.w;
#pragma unroll
  for (int m = 1; m < 64; m <<= 1) {
    s  += __shfl_xor(s, m);
    s2 += __shfl_xor(s2, m);
  }
  __shared__ float red[8];
  if ((t & 63) == 0) { red[t >> 6] = s; red[4 + (t >> 6)] = s2; }
  __syncthreads();
  s  = red[0] + red[1] + red[2] + red[3];
  s2 = red[4] + red[5] + red[6] + red[7];
  const float mu = s * (1.f / DMODEL);
  const float rs = rsqrtf(s2 * (1.f / DMODEL) - mu * mu + 1e-5f);
  const float4 gv = ((const float4*)g)[t];
  const float4 bv = ((const float4*)b)[t];
  short4 o;
  o.x = to_bf16((v.x - mu) * rs * gv.x + bv.x);
  o.y = to_bf16((v.y - mu) * rs * gv.y + bv.y);
  o.z = to_bf16((v.z - mu) * rs * gv.z + bv.z);
  o.w = to_bf16((v.w - mu) * rs * gv.w + bv.w);
  ((short4*)(out + (long)row * DMODEL))[t] = o;
}

// ---------------- NT GEMM: C[M][N] = A[M][K] * Bw[N][K]^T ----------------
template <int EPI>
__global__ __launch_bounds__(256)
void gemm_nt(const short* __restrict__ A, const short* __restrict__ Bw,
             void* __restrict__ Cout, const float* __restrict__ resid,
             int M, int N, int K) {
  __shared__ short As[128 * 32];
  __shared__ short Bs[128 * 32];
  const int tid = threadIdx.x;
  const int w = tid >> 6, lane = tid & 63;
  const int l15 = lane & 15, l4 = lane >> 4;
  const long bm = (long)blockIdx.y * 128, bn = (long)blockIdx.x * 128;
  const int wr = (w >> 1) * 64, wc = (w & 1) * 64;
  f32x4 acc[4][4] = {};
  for (int k0 = 0; k0 < K; k0 += 32) {
    __syncthreads();
#pragma unroll
    for (int i = 0; i < 2; ++i) {
      const int chunk = (i * 4 + w) * 1024;
      const int o = chunk + lane * 16;
      const int row = o >> 6, colb = o & 63;
      lds_load16(A  + (bm + row) * (long)K + k0 + (colb >> 1), (char*)As + chunk);
      lds_load16(Bw + (bn + row) * (long)K + k0 + (colb >> 1), (char*)Bs + chunk);
    }
    __syncthreads();
    bf8 af[4], bfr[4];
#pragma unroll
    for (int m = 0; m < 4; ++m)
      af[m] = *(const bf8*)&As[(wr + m * 16 + l15) * 32 + l4 * 8];
#pragma unroll
    for (int n = 0; n < 4; ++n)
      bfr[n] = *(const bf8*)&Bs[(wc + n * 16 + l15) * 32 + l4 * 8];
#pragma unroll
    for (int m = 0; m < 4; ++m)
#pragma unroll
      for (int n = 0; n < 4; ++n)
        acc[m][n] = __builtin_amdgcn_mfma_f32_16x16x32_bf16(af[m], bfr[n], acc[m][n], 0, 0, 0);
  }
#pragma unroll
  for (int m = 0; m < 4; ++m) {
#pragma unroll
    for (int n = 0; n < 4; ++n) {
      const long col = bn + wc + n * 16 + l15;
#pragma unroll
      for (int r = 0; r < 4; ++r) {
        const long row = bm + wr + m * 16 + l4 * 4 + r;
        float v = acc[m][n][r];
        if (EPI == 0) {
          ((short*)Cout)[row * N + col] = to_bf16(v);
        } else if (EPI == 1) {
          ((short*)Cout)[row * N + col] = to_bf16(v / (1.f + __expf(-v)));
        } else {
          ((float*)Cout)[row * N + col] = resid[row * N + col] + v;
        }
      }
    }
  }
}

// ---------------- Flash attention: 1 warp = 32 q rows, no K/V LDS ----------------
// qk: [NTOK][2048] bf16 (Q cols 0..1023, K cols 1024..2047), vtg: [D][NTOK]
__global__ __launch_bounds__(64, 2)
void attn_kernel(const short* __restrict__ qk, const short* __restrict__ vtg,
                 const short* __restrict__ xn, float* __restrict__ att) {
  const int L = blockIdx.x;
  const int bh = (L & 7) * 4 + ((L >> 3) & 3);   // 4 bh per XCD for L2 locality
  const int qtile = 63 - (L >> 5);               // heavy q-tiles dispatched first
  const int b = bh >> 4, h = bh & 15;
  const int q0 = qtile * 32;
  const int lane = threadIdx.x;
  const int l31 = lane & 31, hi = lane >> 5;
  const long tokbase = (long)b * SEQT;

  // Q B-fragments (persistent): lane -> q-row q0+l31, chunk c covers hw k=c*16+hi*8..+7
  bf8 qf[4];
  {
    const short* qrow = qk + (tokbase + q0 + l31) * 2048 + h * HWID + hi * 8;
#pragma unroll
    for (int c = 0; c < 4; ++c) qf[c] = *(const bf8*)(qrow + c * 16);
  }

  const float slope2 = exp2f(-0.5f * (float)(h + 1)) * 1.44269504f; // slope/ln2
  const float sc2 = 0.125f * 1.44269504f;
  // per-reg alibi constants: krel(r,hi) = (r&3) + 8*(r>>2) + 4*hi
  float arr[16];
#pragma unroll
  for (int r = 0; r < 16; ++r) arr[r] = slope2 * (float)((r & 3) + 8 * (r >> 2));
  const float hofs = slope2 * 4.f * (float)hi;
  const float qabs = (float)(q0 + l31);

  float m2 = -1e30f, lsum = 0.f;
  f32x16 acc0 = {}, acc1 = {};
  const int ktm = q0 >> 6;  // last tile == the (only) masked tile
  const short* kbase = qk + 1024 + h * HWID + hi * 8;
  const short* vbase = vtg + ((long)(h * HWID + l31)) * NTOK + tokbase;

  for (int kt = 0; kt <= ktm; ++kt) {
    const int k0 = kt * 64;
    // ---- QK^T (swapped): S^T tiles, lane holds 32 k-scores of one q-row ----
    f32x16 s0 = {}, s1 = {};
    const short* krow0 = kbase + (tokbase + k0 + l31) * 2048;
    const short* krow1 = krow0 + 32 * 2048;
#pragma unroll
    for (int c = 0; c < 4; ++c) {
      bf8 kf0 = *(const bf8*)(krow0 + c * 16);
      bf8 kf1 = *(const bf8*)(krow1 + c * 16);
      s0 = __builtin_amdgcn_mfma_f32_32x32x16_bf16(kf0, qf[c], s0, 0, 0, 0);
      s1 = __builtin_amdgcn_mfma_f32_32x32x16_bf16(kf1, qf[c], s1, 0, 0, 0);
    }
    // ---- scale + alibi (log2 domain) + causal mask on diagonal tile ----
    const float base = slope2 * ((float)k0 - qabs) + hofs;
    float s[32];
#pragma unroll
    for (int r = 0; r < 16; ++r) {
      s[r]      = fmaf(s0[r], sc2, base + arr[r]);
      s[16 + r] = fmaf(s1[r], sc2, base + arr[r] + slope2 * 32.f);
    }
    if (kt == ktm) {
      const int qi = q0 + l31;
#pragma unroll
      for (int r = 0; r < 16; ++r) {
        const int krel = (r & 3) + 8 * (r >> 2) + 4 * hi;
        if (k0 + krel > qi)      s[r]      = -1e30f;
        if (k0 + 32 + krel > qi) s[16 + r] = -1e30f;
      }
    }
    // ---- row max (in-lane tree + cross-half) ----
    float ma = s[0], mb = s[1], mc = s[2], md = s[3];
#pragma unroll
    for (int i = 4; i < 32; i += 4) {
      ma = fmaxf(ma, s[i]); mb = fmaxf(mb, s[i + 1]);
      mc = fmaxf(mc, s[i + 2]); md = fmaxf(md, s[i + 3]);
    }
    float pm = fmaxf(fmaxf(ma, mb), fmaxf(mc, md));
    pm = fmaxf(pm, __shfl_xor(pm, 32));
    // ---- defer-max rescale (T13) ----
    if (!__all(pm - m2 <= 11.0f)) {
      const float nm = fmaxf(m2, pm);
      const float alpha = exp2_fast(m2 - nm);
      m2 = nm;
      lsum *= alpha;
      acc0 *= alpha;
      acc1 *= alpha;
    }
    // ---- P = exp2(s - m2), row sum ----
    float p[32];
#pragma unroll
    for (int i = 0; i < 32; ++i) p[i] = exp2_fast(s[i] - m2);
    float sa = p[0], sb = p[1], sc = p[2], sd = p[3];
#pragma unroll
    for (int i = 4; i < 32; i += 4) {
      sa += p[i]; sb += p[i + 1]; sc += p[i + 2]; sd += p[i + 3];
    }
    float rs = (sa + sb) + (sc + sd);
    rs += __shfl_xor(rs, 32);
    lsum += rs;
    // ---- repack P -> PV B-fragments (cvt_pk + permlane32_swap, T12) ----
    unsigned cpk[16];
#pragma unroll
    for (int g = 0; g < 8; ++g) {
      cpk[g]     = cvt_pk_bf16(p[2 * g], p[2 * g + 1]);
      cpk[8 + g] = cvt_pk_bf16(p[16 + 2 * g], p[16 + 2 * g + 1]);
    }
    bf8 pb[4];
#pragma unroll
    for (int ch = 0; ch < 4; ++ch) {
      const int cb = (ch >> 1) * 8 + (ch & 1) * 4;  // base into cpk per 16-k chunk
      unsigned u0 = cpk[cb + 0], u2 = cpk[cb + 2];
      unsigned u1 = cpk[cb + 1], u3 = cpk[cb + 3];
      asm("v_permlane32_swap_b32 %0, %1" : "+v"(u0), "+v"(u2));
      asm("v_permlane32_swap_b32 %0, %1" : "+v"(u1), "+v"(u3));
      union { unsigned u[4]; bf8 v; } f;
      f.u[0] = u0; f.u[1] = u1; f.u[2] = u2; f.u[3] = u3;
      pb[ch] = f.v;
    }
    // ---- PV: O^T += V^T · P  (lane keeps its own q column -> scalar rescale) ----
    const short* vrow = vbase + k0;
#pragma unroll
    for (int ch = 0; ch < 4; ++ch) {
      bf8 vf0 = *(const bf8*)(vrow + ch * 16 + hi * 8);
      bf8 vf1 = *(const bf8*)(vrow + (long)32 * NTOK + ch * 16 + hi * 8);
      acc0 = __builtin_amdgcn_mfma_f32_32x32x16_bf16(vf0, pb[ch], acc0, 0, 0, 0);
      acc1 = __builtin_amdgcn_mfma_f32_32x32x16_bf16(vf1, pb[ch], acc1, 0, 0, 0);
    }
  }

  // ---- epilogue: transpose O^T via LDS, add xn residual, coalesced f32x4 stores ----
  __shared__ float Os[32 * 68];
  const float rl = 1.f / lsum;
#pragma unroll
  for (int r = 0; r < 16; ++r) {
    const int d0 = (r & 3) + 8 * (r >> 2) + 4 * hi;
    Os[l31 * 68 + d0]      = acc0[r] * rl;
    Os[l31 * 68 + 32 + d0] = acc1[r] * rl;
  }
  __syncthreads();
#pragma unroll
  for (int it = 0; it < 8; ++it) {
    const int idx = it * 64 + lane;
    const int row = idx >> 4, c4 = idx & 15;
    const float4 ov = *(const float4*)&Os[row * 68 + c4 * 4];
    const long gbase = (tokbase + q0 + row) * DMODEL + h * HWID + c4 * 4;
    const short4 xv = *(const short4*)&xn[gbase];
    float4 o;
    o.x = ov.x + from_bf16(xv.x);
    o.y = ov.y + from_bf16(xv.y);
    o.z = ov.z + from_bf16(xv.z);
    o.w = ov.w + from_bf16(xv.w);
    *(float4*)&att[gbase] = o;
  }
}

// ---------------- launcher ----------------
extern "C" void kernel_launch(void* const* d_in, const int* in_sizes, int n_in,
                              void* d_out, int out_size, void* d_ws, size_t ws_size,
                              hipStream_t stream) {
  (void)in_sizes; (void)n_in; (void)out_size; (void)ws_size;
  const float* x  = (const float*)d_in[0];
  const float* Wq = (const float*)d_in[1];
  const float* Wk = (const float*)d_in[2];
  const float* Wv = (const float*)d_in[3];
  const float* W1 = (const float*)d_in[4];
  const float* W2 = (const float*)d_in[5];
  const float* g1 = (const float*)d_in[6];
  const float* b1 = (const float*)d_in[7];
  const float* g2 = (const float*)d_in[8];
  const float* b2 = (const float*)d_in[9];

  char* ws = (char*)d_ws;
  const size_t MB = 1024 * 1024;
  short* xn    = (short*)(ws + 0);        // 8 MB  [NTOK][D]
  short* qkb   = (short*)(ws + 8  * MB);  // 16 MB [NTOK][2048] (Q | K)
  short* vT    = (short*)(ws + 24 * MB);  // 8 MB  [D][NTOK]
  float* att   = (float*)(ws + 32 * MB);  // 16 MB [NTOK][D]
  short* hb    = (short*)(ws + 48 * MB);  // 8 MB  [NTOK][D]
  short* wqk_b = (short*)(ws + 56 * MB);  // 4 MB  [2048][1024] (Wq rows | Wk rows)
  short* wv_b  = (short*)(ws + 60 * MB);  // 2 MB
  short* w1_b  = (short*)(ws + 62 * MB);  // 8 MB
  short* w2_b  = (short*)(ws + 70 * MB);  // 8 MB
  short* m1    = (short*)(ws + 0);        // 32 MB [NTOK][FF] (aliases xn/qk/vT, dead by then)

  cvt_kernel<<<1024, 256, 0, stream>>>(Wq, wqk_b, 262144);
  cvt_kernel<<<1024, 256, 0, stream>>>(Wk, wqk_b + 1048576, 262144);
  cvt_kernel<<<1024, 256, 0, stream>>>(Wv, wv_b, 262144);
  cvt_kernel<<<4096, 256, 0, stream>>>(W1, w1_b, 1048576);
  cvt_kernel<<<4096, 256, 0, stream>>>(W2, w2_b, 1048576);

  ln_kernel<<<NTOK, 256, 0, stream>>>(x, g1, b1, xn);

  // fused Q|K GEMM: [NTOK][2048]
  gemm_nt<0><<<dim3(16, 32), 256, 0, stream>>>(xn, wqk_b, qkb, nullptr, NTOK, 2048, DMODEL);
  // V^T GEMM: [D][NTOK]
  gemm_nt<0><<<dim3(32, 8), 256, 0, stream>>>(wv_b, xn, vT, nullptr, DMODEL, NTOK, DMODEL);

  attn_kernel<<<2048, 64, 0, stream>>>(qkb, vT, xn, att);

  ln_kernel<<<NTOK, 256, 0, stream>>>(att, g2, b2, hb);

  gemm_nt<1><<<dim3(32, 32), 256, 0, stream>>>(hb, w1_b, m1, nullptr, NTOK, FFDIM, DMODEL);
  gemm_nt<2><<<dim3(8, 32), 256, 0, stream>>>(m1, w2_b, d_out, att, NTOK, DMODEL, FFDIM);
}

// Round 3
// 245.144 us; speedup vs baseline: 1.5430x; 1.2507x over previous
//
#include <hip/hip_runtime.h>

#define DMODEL 1024
#define NHEAD  16
#define HWID   64
#define FFDIM  4096
#define NBATCH 2
#define SEQT   2048
#define NTOK   4096   // NBATCH*SEQT
#define QKLD   3072   // qkv row stride

using bf8    = __attribute__((ext_vector_type(8))) short;
using f32x4  = __attribute__((ext_vector_type(4))) float;
using f32x16 = __attribute__((ext_vector_type(16))) float;

__device__ inline short to_bf16(float f) {
  unsigned u = __float_as_uint(f);
  return (short)((u + 0x7fffu + ((u >> 16) & 1u)) >> 16);
}
__device__ inline float from_bf16(short s) {
  return __uint_as_float(((unsigned)(unsigned short)s) << 16);
}
__device__ inline float exp2_fast(float x) {
  float r;
  asm("v_exp_f32 %0, %1" : "=v"(r) : "v"(x));
  return r;
}
__device__ inline unsigned cvt_pk_bf16(float lo, float hi) {
  unsigned r;
  asm("v_cvt_pk_bf16_f32 %0, %1, %2" : "=v"(r) : "v"(lo), "v"(hi));
  return r;
}
__device__ inline void lds_load16(const void* g, void* l) {
  __builtin_amdgcn_global_load_lds(
      (const __attribute__((address_space(1))) void*)g,
      (__attribute__((address_space(3))) void*)l, 16, 0, 0);
}

// ---------------- f32 -> bf16 convert (weights) ----------------
__global__ __launch_bounds__(256)
void cvt_kernel(const float* __restrict__ in, short* __restrict__ out, int n4) {
  int i = blockIdx.x * 256 + threadIdx.x;
  if (i < n4) {
    float4 v = ((const float4*)in)[i];
    short4 o;
    o.x = to_bf16(v.x); o.y = to_bf16(v.y);
    o.z = to_bf16(v.z); o.w = to_bf16(v.w);
    ((short4*)out)[i] = o;
  }
}

// ---------------- LayerNorm (f32 in -> bf16 out) ----------------
__global__ __launch_bounds__(256)
void ln_kernel(const float* __restrict__ x, const float* __restrict__ g,
               const float* __restrict__ b, short* __restrict__ out) {
  const int row = blockIdx.x;
  const int t = threadIdx.x;
  const float4 v = ((const float4*)(x + (long)row * DMODEL))[t];
  float s  = v.x + v.y + v.z + v.w;
  float s2 = v.x * v.x + v.y * v.y + v.z * v.z + v.w * v.w;
#pragma unroll
  for (int m = 1; m < 64; m <<= 1) {
    s  += __shfl_xor(s, m);
    s2 += __shfl_xor(s2, m);
  }
  __shared__ float red[8];
  if ((t & 63) == 0) { red[t >> 6] = s; red[4 + (t >> 6)] = s2; }
  __syncthreads();
  s  = red[0] + red[1] + red[2] + red[3];
  s2 = red[4] + red[5] + red[6] + red[7];
  const float mu = s * (1.f / DMODEL);
  const float rs = rsqrtf(s2 * (1.f / DMODEL) - mu * mu + 1e-5f);
  const float4 gv = ((const float4*)g)[t];
  const float4 bv = ((const float4*)b)[t];
  short4 o;
  o.x = to_bf16((v.x - mu) * rs * gv.x + bv.x);
  o.y = to_bf16((v.y - mu) * rs * gv.y + bv.y);
  o.z = to_bf16((v.z - mu) * rs * gv.z + bv.z);
  o.w = to_bf16((v.w - mu) * rs * gv.w + bv.w);
  ((short4*)(out + (long)row * DMODEL))[t] = o;
}

// ---------------- 8-wave 256x256 NT GEMM, 4-slot ring, counted vmcnt ----
// C[M][N] = A[M][K]*Bw[N][K]^T.  EPI 0: bf16; 1: SiLU bf16; 2: f32 partial.
template <int EPI>
__global__ __launch_bounds__(512)
void gemm8(const short* __restrict__ A, const short* __restrict__ Bw,
           void* __restrict__ Cout, int N, int lda, int ldb,
           int Kslice, long zstride) {
  __shared__ short lds[4][2][8192];   // [slot][A|B][256 rows x 32 cols], 128 KiB
  const int tid = threadIdx.x;
  const int wid = tid >> 6, lane = tid & 63;
  const int wm = wid >> 2, wn = wid & 3;
  const int l15 = lane & 15, l4 = lane >> 4;

  // block swizzle: XCD chunk then 4x4 supertile (needs gx%4==0, gy%4==0, nwg%8==0)
  const int gx = gridDim.x, nwg = gx * gridDim.y;
  const int wg = blockIdx.y * gx + blockIdx.x;
  const int sw = (wg & 7) * (nwg >> 3) + (wg >> 3);
  const int sx = gx >> 2;
  const int st = sw >> 4, w16 = sw & 15;
  const long bm = (long)((st / sx) * 4 + (w16 >> 2)) * 256;
  const long bn = (long)((st % sx) * 4 + (w16 & 3)) * 256;
  const int kofs = blockIdx.z * Kslice;

  // staging source offsets (elements); LDS dest is linear, source pre-swizzled
  long aoff[2], boff[2];
#pragma unroll
  for (int rd = 0; rd < 2; ++rd) {
    const int row = rd * 128 + (tid >> 2);
    const int slog = (tid & 3) ^ ((row >> 1) & 3);
    aoff[rd] = (bm + row) * (long)lda + slog * 8 + kofs;
    boff[rd] = (bn + row) * (long)ldb + slog * 8 + kofs;
  }
  // LDS read byte-offsets (swizzled)
  int offA[8], offB[4];
#pragma unroll
  for (int ph = 0; ph < 2; ++ph)
#pragma unroll
    for (int m = 0; m < 4; ++m) {
      const int row = wm * 128 + ph * 64 + m * 16 + l15;
      offA[ph * 4 + m] = row * 64 + ((l4 ^ ((row >> 1) & 3)) << 4);
    }
#pragma unroll
  for (int n = 0; n < 4; ++n) {
    const int row = wn * 64 + n * 16 + l15;
    offB[n] = row * 64 + ((l4 ^ ((row >> 1) & 3)) << 4);
  }

  const int NT = Kslice >> 5;
  f32x4 acc[8][4] = {};

  // prologue: stage tiles 0,1,2 (12 loads/wave), wait tile0 (vmcnt 8)
#pragma unroll
  for (int t = 0; t < 3; ++t) {
    char* sb = (char*)&lds[t][0][0] + wid * 1024;
    lds_load16(A  + aoff[0] + t * 32, sb);
    lds_load16(A  + aoff[1] + t * 32, sb + 8192);
    lds_load16(Bw + boff[0] + t * 32, sb + 16384);
    lds_load16(Bw + boff[1] + t * 32, sb + 24576);
  }
  asm volatile("s_waitcnt vmcnt(8)" ::: "memory");
  __builtin_amdgcn_s_barrier();
  asm volatile("" ::: "memory");

  for (int t = 0; t < NT; ++t) {
    const char* sb = (const char*)&lds[t & 3][0][0];
    char* db = (char*)&lds[(t + 3) & 3][0][0] + wid * 1024;
    const bool pf = (t + 3) < NT;
    const long ks = (long)(t + 3) * 32;
    // ---------- phase 0: rows 0-63 of wave's half ----------
    bf8 a0[4], bb[4];
#pragma unroll
    for (int m = 0; m < 4; ++m) a0[m] = *(const bf8*)(sb + offA[m]);
#pragma unroll
    for (int n = 0; n < 4; ++n) bb[n] = *(const bf8*)(sb + 16384 + offB[n]);
    if (pf) {
      lds_load16(A + aoff[0] + ks, db);
      lds_load16(A + aoff[1] + ks, db + 8192);
    }
    __builtin_amdgcn_s_barrier();
    asm volatile("" ::: "memory");
    __builtin_amdgcn_s_setprio(1);
#pragma unroll
    for (int m = 0; m < 4; ++m)
#pragma unroll
      for (int n = 0; n < 4; ++n)
        acc[m][n] = __builtin_amdgcn_mfma_f32_16x16x32_bf16(a0[m], bb[n], acc[m][n], 0, 0, 0);
    __builtin_amdgcn_s_setprio(0);
    __builtin_amdgcn_s_barrier();
    asm volatile("" ::: "memory");
    // ---------- phase 1: rows 64-127 of wave's half ----------
    bf8 a1[4];
#pragma unroll
    for (int m = 0; m < 4; ++m) a1[m] = *(const bf8*)(sb + offA[4 + m]);
    if (pf) {
      lds_load16(Bw + boff[0] + ks, db + 16384);
      lds_load16(Bw + boff[1] + ks, db + 24576);
    }
    const int rem = NT - 1 - t;
    if (rem >= 3)      asm volatile("s_waitcnt vmcnt(8)" ::: "memory");
    else if (rem == 2) asm volatile("s_waitcnt vmcnt(4)" ::: "memory");
    else if (rem == 1) asm volatile("s_waitcnt vmcnt(0)" ::: "memory");
    __builtin_amdgcn_s_barrier();
    asm volatile("" ::: "memory");
    __builtin_amdgcn_s_setprio(1);
#pragma unroll
    for (int m = 0; m < 4; ++m)
#pragma unroll
      for (int n = 0; n < 4; ++n)
        acc[4 + m][n] = __builtin_amdgcn_mfma_f32_16x16x32_bf16(a1[m], bb[n], acc[4 + m][n], 0, 0, 0);
    __builtin_amdgcn_s_setprio(0);
    __builtin_amdgcn_s_barrier();
    asm volatile("" ::: "memory");
  }

  // ---------- epilogue ----------
  float* Cp = (float*)Cout + blockIdx.z * zstride;
#pragma unroll
  for (int mg = 0; mg < 8; ++mg)
#pragma unroll
    for (int n = 0; n < 4; ++n) {
      const long col = bn + wn * 64 + n * 16 + l15;
#pragma unroll
      for (int r = 0; r < 4; ++r) {
        const long row = bm + wm * 128 + mg * 16 + l4 * 4 + r;
        float v = acc[mg][n][r];
        if (EPI == 0) {
          ((short*)Cout)[row * N + col] = to_bf16(v);
        } else if (EPI == 1) {
          ((short*)Cout)[row * N + col] = to_bf16(v / (1.f + __expf(-v)));
        } else {
          Cp[row * N + col] = v;
        }
      }
    }
}

// ---------------- V transpose: qkv[:,2048+d] -> vT[d][tok] ----------------
__global__ __launch_bounds__(256)
void transpose_v(const short* __restrict__ qkv, short* __restrict__ vT) {
  __shared__ short tile[64][72];
  const int bt = blockIdx.x * 64;   // token base
  const int bd = blockIdx.y * 64;   // d base
  const int tid = threadIdx.x;
  const int r = tid >> 2, c = (tid & 3) * 16;
  *(bf8*)&tile[r][c] =
      *(const bf8*)&qkv[(long)(bt + r) * QKLD + 2048 + bd + c];
  *(bf8*)&tile[r][c + 8] =
      *(const bf8*)&qkv[(long)(bt + r) * QKLD + 2048 + bd + c + 8];
  __syncthreads();
  short o[16];
#pragma unroll
  for (int j = 0; j < 16; ++j) o[j] = tile[c + j][r];
  *(bf8*)&vT[(long)(bd + r) * NTOK + bt + c]     = *(bf8*)&o[0];
  *(bf8*)&vT[(long)(bd + r) * NTOK + bt + c + 8] = *(bf8*)&o[8];
}

// ---------------- Flash attention: 1 warp = 32 q rows, no K/V LDS ----------
__global__ __launch_bounds__(64, 2)
void attn_kernel(const short* __restrict__ qkv, const short* __restrict__ vtg,
                 const short* __restrict__ xn, float* __restrict__ att) {
  const int L = blockIdx.x;
  const int bh = (L & 7) * 4 + ((L >> 3) & 3);   // 4 bh per XCD for L2 locality
  const int qtile = 63 - (L >> 5);               // heavy q-tiles dispatched first
  const int b = bh >> 4, h = bh & 15;
  const int q0 = qtile * 32;
  const int lane = threadIdx.x;
  const int l31 = lane & 31, hi = lane >> 5;
  const long tokbase = (long)b * SEQT;

  bf8 qf[4];
  {
    const short* qrow = qkv + (tokbase + q0 + l31) * QKLD + h * HWID + hi * 8;
#pragma unroll
    for (int c = 0; c < 4; ++c) qf[c] = *(const bf8*)(qrow + c * 16);
  }

  const float slope2 = exp2f(-0.5f * (float)(h + 1)) * 1.44269504f;
  const float sc2 = 0.125f * 1.44269504f;
  float arr[16];
#pragma unroll
  for (int r = 0; r < 16; ++r) arr[r] = slope2 * (float)((r & 3) + 8 * (r >> 2));
  const float hofs = slope2 * 4.f * (float)hi;
  const float qabs = (float)(q0 + l31);

  float m2 = -1e30f, lsum = 0.f;
  f32x16 acc0 = {}, acc1 = {};
  const int ktm = q0 >> 6;
  const short* kbase = qkv + 1024 + h * HWID + hi * 8;
  const short* vbase = vtg + ((long)(h * HWID + l31)) * NTOK + tokbase;

  for (int kt = 0; kt <= ktm; ++kt) {
    const int k0 = kt * 64;
    f32x16 s0 = {}, s1 = {};
    const short* krow0 = kbase + (tokbase + k0 + l31) * QKLD;
    const short* krow1 = krow0 + 32 * QKLD;
#pragma unroll
    for (int c = 0; c < 4; ++c) {
      bf8 kf0 = *(const bf8*)(krow0 + c * 16);
      bf8 kf1 = *(const bf8*)(krow1 + c * 16);
      s0 = __builtin_amdgcn_mfma_f32_32x32x16_bf16(kf0, qf[c], s0, 0, 0, 0);
      s1 = __builtin_amdgcn_mfma_f32_32x32x16_bf16(kf1, qf[c], s1, 0, 0, 0);
    }
    const float base = slope2 * ((float)k0 - qabs) + hofs;
    float s[32];
#pragma unroll
    for (int r = 0; r < 16; ++r) {
      s[r]      = fmaf(s0[r], sc2, base + arr[r]);
      s[16 + r] = fmaf(s1[r], sc2, base + arr[r] + slope2 * 32.f);
    }
    if (kt == ktm) {
      const int qi = q0 + l31;
#pragma unroll
      for (int r = 0; r < 16; ++r) {
        const int krel = (r & 3) + 8 * (r >> 2) + 4 * hi;
        if (k0 + krel > qi)      s[r]      = -1e30f;
        if (k0 + 32 + krel > qi) s[16 + r] = -1e30f;
      }
    }
    float ma = s[0], mb = s[1], mc = s[2], md = s[3];
#pragma unroll
    for (int i = 4; i < 32; i += 4) {
      ma = fmaxf(ma, s[i]); mb = fmaxf(mb, s[i + 1]);
      mc = fmaxf(mc, s[i + 2]); md = fmaxf(md, s[i + 3]);
    }
    float pm = fmaxf(fmaxf(ma, mb), fmaxf(mc, md));
    pm = fmaxf(pm, __shfl_xor(pm, 32));
    if (!__all(pm - m2 <= 11.0f)) {
      const float nm = fmaxf(m2, pm);
      const float alpha = exp2_fast(m2 - nm);
      m2 = nm;
      lsum *= alpha;
      acc0 *= alpha;
      acc1 *= alpha;
    }
    float p[32];
#pragma unroll
    for (int i = 0; i < 32; ++i) p[i] = exp2_fast(s[i] - m2);
    float sa = p[0], sb = p[1], sc = p[2], sd = p[3];
#pragma unroll
    for (int i = 4; i < 32; i += 4) {
      sa += p[i]; sb += p[i + 1]; sc += p[i + 2]; sd += p[i + 3];
    }
    float rs = (sa + sb) + (sc + sd);
    rs += __shfl_xor(rs, 32);
    lsum += rs;
    unsigned cpk[16];
#pragma unroll
    for (int g = 0; g < 8; ++g) {
      cpk[g]     = cvt_pk_bf16(p[2 * g], p[2 * g + 1]);
      cpk[8 + g] = cvt_pk_bf16(p[16 + 2 * g], p[16 + 2 * g + 1]);
    }
    bf8 pb[4];
#pragma unroll
    for (int ch = 0; ch < 4; ++ch) {
      const int cb = (ch >> 1) * 8 + (ch & 1) * 4;
      unsigned u0 = cpk[cb + 0], u2 = cpk[cb + 2];
      unsigned u1 = cpk[cb + 1], u3 = cpk[cb + 3];
      asm("v_permlane32_swap_b32 %0, %1" : "+v"(u0), "+v"(u2));
      asm("v_permlane32_swap_b32 %0, %1" : "+v"(u1), "+v"(u3));
      union { unsigned u[4]; bf8 v; } f;
      f.u[0] = u0; f.u[1] = u1; f.u[2] = u2; f.u[3] = u3;
      pb[ch] = f.v;
    }
    const short* vrow = vbase + k0;
#pragma unroll
    for (int ch = 0; ch < 4; ++ch) {
      bf8 vf0 = *(const bf8*)(vrow + ch * 16 + hi * 8);
      bf8 vf1 = *(const bf8*)(vrow + (long)32 * NTOK + ch * 16 + hi * 8);
      acc0 = __builtin_amdgcn_mfma_f32_32x32x16_bf16(vf0, pb[ch], acc0, 0, 0, 0);
      acc1 = __builtin_amdgcn_mfma_f32_32x32x16_bf16(vf1, pb[ch], acc1, 0, 0, 0);
    }
  }

  __shared__ float Os[32 * 68];
  const float rl = 1.f / lsum;
#pragma unroll
  for (int r = 0; r < 16; ++r) {
    const int d0 = (r & 3) + 8 * (r >> 2) + 4 * hi;
    Os[l31 * 68 + d0]      = acc0[r] * rl;
    Os[l31 * 68 + 32 + d0] = acc1[r] * rl;
  }
  __syncthreads();
#pragma unroll
  for (int it = 0; it < 8; ++it) {
    const int idx = it * 64 + lane;
    const int row = idx >> 4, c4 = idx & 15;
    const float4 ov = *(const float4*)&Os[row * 68 + c4 * 4];
    const long gbase = (tokbase + q0 + row) * DMODEL + h * HWID + c4 * 4;
    const short4 xv = *(const short4*)&xn[gbase];
    float4 o;
    o.x = ov.x + from_bf16(xv.x);
    o.y = ov.y + from_bf16(xv.y);
    o.z = ov.z + from_bf16(xv.z);
    o.w = ov.w + from_bf16(xv.w);
    *(float4*)&att[gbase] = o;
  }
}

// ---------------- combine: d_out += sum of 4 split-K partials ----------------
__global__ __launch_bounds__(256)
void combine_kernel(const float* __restrict__ p, float* __restrict__ dout, int n4) {
  int i = blockIdx.x * 256 + threadIdx.x;
  if (i < n4) {
    float4 a  = ((const float4*)dout)[i];
    float4 b0 = ((const float4*)(p))[i];
    float4 b1 = ((const float4*)(p + 4194304))[i];
    float4 b2 = ((const float4*)(p + 8388608))[i];
    float4 b3 = ((const float4*)(p + 12582912))[i];
    a.x += (b0.x + b1.x) + (b2.x + b3.x);
    a.y += (b0.y + b1.y) + (b2.y + b3.y);
    a.z += (b0.z + b1.z) + (b2.z + b3.z);
    a.w += (b0.w + b1.w) + (b2.w + b3.w);
    ((float4*)dout)[i] = a;
  }
}

// ---------------- launcher ----------------
extern "C" void kernel_launch(void* const* d_in, const int* in_sizes, int n_in,
                              void* d_out, int out_size, void* d_ws, size_t ws_size,
                              hipStream_t stream) {
  (void)in_sizes; (void)n_in; (void)out_size; (void)ws_size;
  const float* x  = (const float*)d_in[0];
  const float* Wq = (const float*)d_in[1];
  const float* Wk = (const float*)d_in[2];
  const float* Wv = (const float*)d_in[3];
  const float* W1 = (const float*)d_in[4];
  const float* W2 = (const float*)d_in[5];
  const float* g1 = (const float*)d_in[6];
  const float* b1 = (const float*)d_in[7];
  const float* g2 = (const float*)d_in[8];
  const float* b2 = (const float*)d_in[9];

  char* ws = (char*)d_ws;
  const size_t MB = 1024 * 1024;
  short* wqkv_b = (short*)(ws + 0);        // 6 MB [3072][1024]
  short* w1_b   = (short*)(ws + 6  * MB);  // 8 MB
  short* w2_b   = (short*)(ws + 14 * MB);  // 8 MB
  short* xn     = (short*)(ws + 22 * MB);  // 8 MB [NTOK][D]
  short* qkv    = (short*)(ws + 30 * MB);  // 24 MB [NTOK][3072]
  short* m1     = (short*)(ws + 22 * MB);  // 32 MB (aliases xn+qkv after attn)
  short* vT     = (short*)(ws + 54 * MB);  // 8 MB [D][NTOK]
  short* hb     = (short*)(ws + 62 * MB);  // 8 MB [NTOK][D]
  float* parts  = (float*)(ws + 54 * MB);  // 64 MB (aliases vT+hb after mlp1)
  float* att    = (float*)d_out;           // att lives in d_out (resid for combine)

  cvt_kernel<<<1024, 256, 0, stream>>>(Wq, wqkv_b, 262144);
  cvt_kernel<<<1024, 256, 0, stream>>>(Wk, wqkv_b + 1048576, 262144);
  cvt_kernel<<<1024, 256, 0, stream>>>(Wv, wqkv_b + 2097152, 262144);
  cvt_kernel<<<4096, 256, 0, stream>>>(W1, w1_b, 1048576);
  cvt_kernel<<<4096, 256, 0, stream>>>(W2, w2_b, 1048576);

  ln_kernel<<<NTOK, 256, 0, stream>>>(x, g1, b1, xn);

  // fused QKV: [NTOK][3072] = xn * wqkv^T
  gemm8<0><<<dim3(12, 16), 512, 0, stream>>>(xn, wqkv_b, qkv, QKLD, DMODEL, DMODEL,
                                             DMODEL, 0);
  transpose_v<<<dim3(64, 16), 256, 0, stream>>>(qkv, vT);

  attn_kernel<<<2048, 64, 0, stream>>>(qkv, vT, xn, att);

  ln_kernel<<<NTOK, 256, 0, stream>>>(att, g2, b2, hb);

  // MLP1: m1 = silu(hb * w1^T)
  gemm8<1><<<dim3(16, 16), 512, 0, stream>>>(hb, w1_b, m1, FFDIM, DMODEL, DMODEL,
                                             DMODEL, 0);
  // MLP2 split-K=4: parts[z] = m1[:, z*1024:(z+1)*1024] * w2^T slice
  gemm8<2><<<dim3(4, 16, 4), 512, 0, stream>>>(m1, w2_b, parts, DMODEL, FFDIM, FFDIM,
                                               1024, (long)NTOK * DMODEL);
  combine_kernel<<<4096, 256, 0, stream>>>(parts, (float*)d_out, 1048576);
}

// Round 4
// 216.150 us; speedup vs baseline: 1.7500x; 1.1341x over previous
//
#include <hip/hip_runtime.h>

#define DMODEL 1024
#define NHEAD  16
#define HWID   64
#define FFDIM  4096
#define NBATCH 2
#define SEQT   2048
#define NTOK   4096   // NBATCH*SEQT
#define QKLD   3072   // qkv row stride

using bf8    = __attribute__((ext_vector_type(8))) short;
using f32x4  = __attribute__((ext_vector_type(4))) float;
using f32x16 = __attribute__((ext_vector_type(16))) float;

__device__ inline short to_bf16(float f) {
  unsigned u = __float_as_uint(f);
  return (short)((u + 0x7fffu + ((u >> 16) & 1u)) >> 16);
}
__device__ inline float from_bf16(short s) {
  return __uint_as_float(((unsigned)(unsigned short)s) << 16);
}
__device__ inline float exp2_fast(float x) {
  float r;
  asm("v_exp_f32 %0, %1" : "=v"(r) : "v"(x));
  return r;
}
__device__ inline unsigned cvt_pk_bf16(float lo, float hi) {
  unsigned r;
  asm("v_cvt_pk_bf16_f32 %0, %1, %2" : "=v"(r) : "v"(lo), "v"(hi));
  return r;
}
__device__ inline void lds_load16(const void* g, void* l) {
  __builtin_amdgcn_global_load_lds(
      (const __attribute__((address_space(1))) void*)g,
      (__attribute__((address_space(3))) void*)l, 16, 0, 0);
}

// ---------------- f32 -> bf16 convert (weights) ----------------
__global__ __launch_bounds__(256)
void cvt_kernel(const float* __restrict__ in, short* __restrict__ out, int n4) {
  int i = blockIdx.x * 256 + threadIdx.x;
  if (i < n4) {
    float4 v = ((const float4*)in)[i];
    short4 o;
    o.x = to_bf16(v.x); o.y = to_bf16(v.y);
    o.z = to_bf16(v.z); o.w = to_bf16(v.w);
    ((short4*)out)[i] = o;
  }
}

// ---------------- LayerNorm (f32 in -> bf16 out) ----------------
__global__ __launch_bounds__(256)
void ln_kernel(const float* __restrict__ x, const float* __restrict__ g,
               const float* __restrict__ b, short* __restrict__ out) {
  const int row = blockIdx.x;
  const int t = threadIdx.x;
  const float4 v = ((const float4*)(x + (long)row * DMODEL))[t];
  float s  = v.x + v.y + v.z + v.w;
  float s2 = v.x * v.x + v.y * v.y + v.z * v.z + v.w * v.w;
#pragma unroll
  for (int m = 1; m < 64; m <<= 1) {
    s  += __shfl_xor(s, m);
    s2 += __shfl_xor(s2, m);
  }
  __shared__ float red[8];
  if ((t & 63) == 0) { red[t >> 6] = s; red[4 + (t >> 6)] = s2; }
  __syncthreads();
  s  = red[0] + red[1] + red[2] + red[3];
  s2 = red[4] + red[5] + red[6] + red[7];
  const float mu = s * (1.f / DMODEL);
  const float rs = rsqrtf(s2 * (1.f / DMODEL) - mu * mu + 1e-5f);
  const float4 gv = ((const float4*)g)[t];
  const float4 bv = ((const float4*)b)[t];
  short4 o;
  o.x = to_bf16((v.x - mu) * rs * gv.x + bv.x);
  o.y = to_bf16((v.y - mu) * rs * gv.y + bv.y);
  o.z = to_bf16((v.z - mu) * rs * gv.z + bv.z);
  o.w = to_bf16((v.w - mu) * rs * gv.w + bv.w);
  ((short4*)(out + (long)row * DMODEL))[t] = o;
}

// ---------------- 8-wave 256x256 NT GEMM, 4-slot ring, counted vmcnt ----
template <int EPI>
__global__ __launch_bounds__(512)
void gemm8(const short* __restrict__ A, const short* __restrict__ Bw,
           void* __restrict__ Cout, int N, int lda, int ldb,
           int Kslice, long zstride) {
  __shared__ short lds[4][2][8192];
  const int tid = threadIdx.x;
  const int wid = tid >> 6, lane = tid & 63;
  const int wm = wid >> 2, wn = wid & 3;
  const int l15 = lane & 15, l4 = lane >> 4;

  const int gx = gridDim.x, nwg = gx * gridDim.y;
  const int wg = blockIdx.y * gx + blockIdx.x;
  const int sw = (wg & 7) * (nwg >> 3) + (wg >> 3);
  const int sx = gx >> 2;
  const int st = sw >> 4, w16 = sw & 15;
  const long bm = (long)((st / sx) * 4 + (w16 >> 2)) * 256;
  const long bn = (long)((st % sx) * 4 + (w16 & 3)) * 256;
  const int kofs = blockIdx.z * Kslice;

  long aoff[2], boff[2];
#pragma unroll
  for (int rd = 0; rd < 2; ++rd) {
    const int row = rd * 128 + (tid >> 2);
    const int slog = (tid & 3) ^ ((row >> 1) & 3);
    aoff[rd] = (bm + row) * (long)lda + slog * 8 + kofs;
    boff[rd] = (bn + row) * (long)ldb + slog * 8 + kofs;
  }
  int offA[8], offB[4];
#pragma unroll
  for (int ph = 0; ph < 2; ++ph)
#pragma unroll
    for (int m = 0; m < 4; ++m) {
      const int row = wm * 128 + ph * 64 + m * 16 + l15;
      offA[ph * 4 + m] = row * 64 + ((l4 ^ ((row >> 1) & 3)) << 4);
    }
#pragma unroll
  for (int n = 0; n < 4; ++n) {
    const int row = wn * 64 + n * 16 + l15;
    offB[n] = row * 64 + ((l4 ^ ((row >> 1) & 3)) << 4);
  }

  const int NT = Kslice >> 5;
  f32x4 acc[8][4] = {};

#pragma unroll
  for (int t = 0; t < 3; ++t) {
    char* sb = (char*)&lds[t][0][0] + wid * 1024;
    lds_load16(A  + aoff[0] + t * 32, sb);
    lds_load16(A  + aoff[1] + t * 32, sb + 8192);
    lds_load16(Bw + boff[0] + t * 32, sb + 16384);
    lds_load16(Bw + boff[1] + t * 32, sb + 24576);
  }
  asm volatile("s_waitcnt vmcnt(8)" ::: "memory");
  __builtin_amdgcn_s_barrier();
  asm volatile("" ::: "memory");

  for (int t = 0; t < NT; ++t) {
    const char* sb = (const char*)&lds[t & 3][0][0];
    char* db = (char*)&lds[(t + 3) & 3][0][0] + wid * 1024;
    const bool pf = (t + 3) < NT;
    const long ks = (long)(t + 3) * 32;
    bf8 a0[4], bb[4];
#pragma unroll
    for (int m = 0; m < 4; ++m) a0[m] = *(const bf8*)(sb + offA[m]);
#pragma unroll
    for (int n = 0; n < 4; ++n) bb[n] = *(const bf8*)(sb + 16384 + offB[n]);
    if (pf) {
      lds_load16(A + aoff[0] + ks, db);
      lds_load16(A + aoff[1] + ks, db + 8192);
    }
    __builtin_amdgcn_s_barrier();
    asm volatile("" ::: "memory");
    __builtin_amdgcn_s_setprio(1);
#pragma unroll
    for (int m = 0; m < 4; ++m)
#pragma unroll
      for (int n = 0; n < 4; ++n)
        acc[m][n] = __builtin_amdgcn_mfma_f32_16x16x32_bf16(a0[m], bb[n], acc[m][n], 0, 0, 0);
    __builtin_amdgcn_s_setprio(0);
    __builtin_amdgcn_s_barrier();
    asm volatile("" ::: "memory");
    bf8 a1[4];
#pragma unroll
    for (int m = 0; m < 4; ++m) a1[m] = *(const bf8*)(sb + offA[4 + m]);
    if (pf) {
      lds_load16(Bw + boff[0] + ks, db + 16384);
      lds_load16(Bw + boff[1] + ks, db + 24576);
    }
    const int rem = NT - 1 - t;
    if (rem >= 3)      asm volatile("s_waitcnt vmcnt(8)" ::: "memory");
    else if (rem == 2) asm volatile("s_waitcnt vmcnt(4)" ::: "memory");
    else if (rem == 1) asm volatile("s_waitcnt vmcnt(0)" ::: "memory");
    __builtin_amdgcn_s_barrier();
    asm volatile("" ::: "memory");
    __builtin_amdgcn_s_setprio(1);
#pragma unroll
    for (int m = 0; m < 4; ++m)
#pragma unroll
      for (int n = 0; n < 4; ++n)
        acc[4 + m][n] = __builtin_amdgcn_mfma_f32_16x16x32_bf16(a1[m], bb[n], acc[4 + m][n], 0, 0, 0);
    __builtin_amdgcn_s_setprio(0);
    __builtin_amdgcn_s_barrier();
    asm volatile("" ::: "memory");
  }

  float* Cp = (float*)Cout + blockIdx.z * zstride;
#pragma unroll
  for (int mg = 0; mg < 8; ++mg)
#pragma unroll
    for (int n = 0; n < 4; ++n) {
      const long col = bn + wn * 64 + n * 16 + l15;
#pragma unroll
      for (int r = 0; r < 4; ++r) {
        const long row = bm + wm * 128 + mg * 16 + l4 * 4 + r;
        float v = acc[mg][n][r];
        if (EPI == 0) {
          ((short*)Cout)[row * N + col] = to_bf16(v);
        } else if (EPI == 1) {
          ((short*)Cout)[row * N + col] = to_bf16(v / (1.f + __expf(-v)));
        } else {
          Cp[row * N + col] = v;
        }
      }
    }
}

// ---------------- K pack: qkv K-cols -> MFMA-fragment order ----------------
// Kp[bh][g(32tok)][c(4 d-chunks)][lane64] : lane hi*32+row holds
//   K[b*2048+g*32+row][h*64 + c*16 + hi*8 .. +7]
__global__ __launch_bounds__(256)
void pack_k(const short* __restrict__ qkv, short* __restrict__ Kp) {
  const int g = blockIdx.x, bh = blockIdx.y;
  const int b = bh >> 4, h = bh & 15;
  const int t = threadIdx.x;
  const int row = t >> 3, cc = t & 7, c = cc >> 1, hi = cc & 1;
  const bf8 v = *(const bf8*)&qkv[(long)(b * SEQT + g * 32 + row) * QKLD +
                                  1024 + h * HWID + c * 16 + hi * 8];
  *(bf8*)&Kp[(((long)bh * 256 + g * 4 + c) * 64 + hi * 32 + row) * 8] = v;
}

// ---------------- V pack: qkv V-cols -> transposed MFMA-fragment order ----
// Vp[bh][dg(2)][chg(128 of 16tok)][lane64] : lane hi*32+row holds
//   V[b*2048+chg*16+hi*8+j][h*64 + dg*32 + row]  (j=0..7)
__global__ __launch_bounds__(256)
void pack_v(const short* __restrict__ qkv, short* __restrict__ Vp) {
  __shared__ short tile[64][72];
  const int tc = blockIdx.x, bh = blockIdx.y;
  const int b = bh >> 4, h = bh & 15;
  const int t = threadIdx.x;
  {
    const int r = t >> 2, c = (t & 3) * 16;
    const long src = (long)(b * SEQT + tc * 64 + r) * QKLD + 2048 + h * HWID + c;
    *(bf8*)&tile[r][c]     = *(const bf8*)&qkv[src];
    *(bf8*)&tile[r][c + 8] = *(const bf8*)&qkv[src + 8];
  }
  __syncthreads();
  const int dg = t >> 7, ch = (t >> 5) & 3, row = t & 31;
#pragma unroll
  for (int hi = 0; hi < 2; ++hi) {
    short o[8];
#pragma unroll
    for (int j = 0; j < 8; ++j) o[j] = tile[ch * 16 + hi * 8 + j][dg * 32 + row];
    *(bf8*)&Vp[(((long)bh * 256 + dg * 128 + tc * 4 + ch) * 64 + hi * 32 + row) * 8] =
        *(bf8*)o;
  }
}

// ---------------- Flash attention: 1 warp = 32 q rows, packed K/V frags ----
__global__ __launch_bounds__(64, 2)
void attn_kernel(const short* __restrict__ qkv, const short* __restrict__ Kp,
                 const short* __restrict__ Vp, const short* __restrict__ xn,
                 float* __restrict__ att) {
  const int L = blockIdx.x;
  const int bh = (L & 7) * 4 + ((L >> 3) & 3);   // 4 bh per XCD for L2 locality
  const int qtile = 63 - (L >> 5);
  const int b = bh >> 4, h = bh & 15;
  const int q0 = qtile * 32;
  const int lane = threadIdx.x;
  const int l31 = lane & 31, hi = lane >> 5;
  const long tokbase = (long)b * SEQT;

  bf8 qf[4];
  {
    const short* qrow = qkv + (tokbase + q0 + l31) * QKLD + h * HWID + hi * 8;
#pragma unroll
    for (int c = 0; c < 4; ++c) qf[c] = *(const bf8*)(qrow + c * 16);
  }

  const float slope2 = exp2f(-0.5f * (float)(h + 1)) * 1.44269504f;
  const float sc2 = 0.125f * 1.44269504f;
  float arr[16];
#pragma unroll
  for (int r = 0; r < 16; ++r) arr[r] = slope2 * (float)((r & 3) + 8 * (r >> 2));
  const float hofs = slope2 * 4.f * (float)hi;
  const float qabs = (float)(q0 + l31);

  float m2 = -1e30f, lsum = 0.f;
  f32x16 acc0 = {}, acc1 = {};
  const int ktm = q0 >> 6;
  // fragment bases (bf8 units), lane folded in
  const bf8* kfb = (const bf8*)Kp + (long)bh * 16384 + lane;
  const bf8* vfb = (const bf8*)Vp + (long)bh * 16384 + lane;

  bf8 kc[8], kn[8], vc[8];
#pragma unroll
  for (int c = 0; c < 4; ++c) {
    kc[c]     = kfb[c * 64];
    kc[4 + c] = kfb[256 + c * 64];
  }

#pragma unroll 2
  for (int kt = 0; kt <= ktm; ++kt) {
    const int k0 = kt * 64;
    // ---- issue V(t) loads (retire under QK+softmax) ----
    const long vb = (long)kt * 256;
#pragma unroll
    for (int ch = 0; ch < 4; ++ch) {
      vc[ch]     = vfb[vb + ch * 64];
      vc[4 + ch] = vfb[8192 + vb + ch * 64];
    }
    // ---- issue K(t+1) loads (retire by next iteration) ----
    const long nb = (long)(kt < ktm ? kt + 1 : kt) * 512;
#pragma unroll
    for (int c = 0; c < 4; ++c) {
      kn[c]     = kfb[nb + c * 64];
      kn[4 + c] = kfb[nb + 256 + c * 64];
    }
    // ---- QK^T (swapped): lane holds 32 k-scores of one q-row ----
    f32x16 s0 = {}, s1 = {};
#pragma unroll
    for (int c = 0; c < 4; ++c) {
      s0 = __builtin_amdgcn_mfma_f32_32x32x16_bf16(kc[c], qf[c], s0, 0, 0, 0);
      s1 = __builtin_amdgcn_mfma_f32_32x32x16_bf16(kc[4 + c], qf[c], s1, 0, 0, 0);
    }
    const float base = slope2 * ((float)k0 - qabs) + hofs;
    float s[32];
#pragma unroll
    for (int r = 0; r < 16; ++r) {
      s[r]      = fmaf(s0[r], sc2, base + arr[r]);
      s[16 + r] = fmaf(s1[r], sc2, base + arr[r] + slope2 * 32.f);
    }
    if (kt == ktm) {
      const int qi = q0 + l31;
#pragma unroll
      for (int r = 0; r < 16; ++r) {
        const int krel = (r & 3) + 8 * (r >> 2) + 4 * hi;
        if (k0 + krel > qi)      s[r]      = -1e30f;
        if (k0 + 32 + krel > qi) s[16 + r] = -1e30f;
      }
    }
    float ma = s[0], mb = s[1], mc = s[2], md = s[3];
#pragma unroll
    for (int i = 4; i < 32; i += 4) {
      ma = fmaxf(ma, s[i]); mb = fmaxf(mb, s[i + 1]);
      mc = fmaxf(mc, s[i + 2]); md = fmaxf(md, s[i + 3]);
    }
    float pm = fmaxf(fmaxf(ma, mb), fmaxf(mc, md));
    pm = fmaxf(pm, __shfl_xor(pm, 32));
    if (!__all(pm - m2 <= 11.0f)) {
      const float nm = fmaxf(m2, pm);
      const float alpha = exp2_fast(m2 - nm);
      m2 = nm;
      lsum *= alpha;
      acc0 *= alpha;
      acc1 *= alpha;
    }
    float p[32];
#pragma unroll
    for (int i = 0; i < 32; ++i) p[i] = exp2_fast(s[i] - m2);
    float sa = p[0], sb = p[1], sc = p[2], sd = p[3];
#pragma unroll
    for (int i = 4; i < 32; i += 4) {
      sa += p[i]; sb += p[i + 1]; sc += p[i + 2]; sd += p[i + 3];
    }
    float rs = (sa + sb) + (sc + sd);
    rs += __shfl_xor(rs, 32);
    lsum += rs;
    unsigned cpk[16];
#pragma unroll
    for (int g = 0; g < 8; ++g) {
      cpk[g]     = cvt_pk_bf16(p[2 * g], p[2 * g + 1]);
      cpk[8 + g] = cvt_pk_bf16(p[16 + 2 * g], p[16 + 2 * g + 1]);
    }
    bf8 pb[4];
#pragma unroll
    for (int ch = 0; ch < 4; ++ch) {
      const int cb = (ch >> 1) * 8 + (ch & 1) * 4;
      unsigned u0 = cpk[cb + 0], u2 = cpk[cb + 2];
      unsigned u1 = cpk[cb + 1], u3 = cpk[cb + 3];
      asm("v_permlane32_swap_b32 %0, %1" : "+v"(u0), "+v"(u2));
      asm("v_permlane32_swap_b32 %0, %1" : "+v"(u1), "+v"(u3));
      union { unsigned u[4]; bf8 v; } f;
      f.u[0] = u0; f.u[1] = u1; f.u[2] = u2; f.u[3] = u3;
      pb[ch] = f.v;
    }
    // ---- PV: O^T += V^T · P ----
#pragma unroll
    for (int ch = 0; ch < 4; ++ch) {
      acc0 = __builtin_amdgcn_mfma_f32_32x32x16_bf16(vc[ch], pb[ch], acc0, 0, 0, 0);
      acc1 = __builtin_amdgcn_mfma_f32_32x32x16_bf16(vc[4 + ch], pb[ch], acc1, 0, 0, 0);
    }
    // ---- rotate K double-buffer (unroll-2 renames these away) ----
#pragma unroll
    for (int i = 0; i < 8; ++i) kc[i] = kn[i];
  }

  __shared__ float Os[32 * 68];
  const float rl = 1.f / lsum;
#pragma unroll
  for (int r = 0; r < 16; ++r) {
    const int d0 = (r & 3) + 8 * (r >> 2) + 4 * hi;
    Os[l31 * 68 + d0]      = acc0[r] * rl;
    Os[l31 * 68 + 32 + d0] = acc1[r] * rl;
  }
  __syncthreads();
#pragma unroll
  for (int it = 0; it < 8; ++it) {
    const int idx = it * 64 + lane;
    const int row = idx >> 4, c4 = idx & 15;
    const float4 ov = *(const float4*)&Os[row * 68 + c4 * 4];
    const long gbase = (tokbase + q0 + row) * DMODEL + h * HWID + c4 * 4;
    const short4 xv = *(const short4*)&xn[gbase];
    float4 o;
    o.x = ov.x + from_bf16(xv.x);
    o.y = ov.y + from_bf16(xv.y);
    o.z = ov.z + from_bf16(xv.z);
    o.w = ov.w + from_bf16(xv.w);
    *(float4*)&att[gbase] = o;
  }
}

// ---------------- combine: d_out += sum of 4 split-K partials ----------------
__global__ __launch_bounds__(256)
void combine_kernel(const float* __restrict__ p, float* __restrict__ dout, int n4) {
  int i = blockIdx.x * 256 + threadIdx.x;
  if (i < n4) {
    float4 a  = ((const float4*)dout)[i];
    float4 b0 = ((const float4*)(p))[i];
    float4 b1 = ((const float4*)(p + 4194304))[i];
    float4 b2 = ((const float4*)(p + 8388608))[i];
    float4 b3 = ((const float4*)(p + 12582912))[i];
    a.x += (b0.x + b1.x) + (b2.x + b3.x);
    a.y += (b0.y + b1.y) + (b2.y + b3.y);
    a.z += (b0.z + b1.z) + (b2.z + b3.z);
    a.w += (b0.w + b1.w) + (b2.w + b3.w);
    ((float4*)dout)[i] = a;
  }
}

// ---------------- launcher ----------------
extern "C" void kernel_launch(void* const* d_in, const int* in_sizes, int n_in,
                              void* d_out, int out_size, void* d_ws, size_t ws_size,
                              hipStream_t stream) {
  (void)in_sizes; (void)n_in; (void)out_size; (void)ws_size;
  const float* x  = (const float*)d_in[0];
  const float* Wq = (const float*)d_in[1];
  const float* Wk = (const float*)d_in[2];
  const float* Wv = (const float*)d_in[3];
  const float* W1 = (const float*)d_in[4];
  const float* W2 = (const float*)d_in[5];
  const float* g1 = (const float*)d_in[6];
  const float* b1 = (const float*)d_in[7];
  const float* g2 = (const float*)d_in[8];
  const float* b2 = (const float*)d_in[9];

  char* ws = (char*)d_ws;
  const size_t MB = 1024 * 1024;
  short* wqkv_b = (short*)(ws + 0);        // 6 MB [3072][1024]
  short* w1_b   = (short*)(ws + 6  * MB);  // 8 MB
  short* w2_b   = (short*)(ws + 14 * MB);  // 8 MB
  short* xn     = (short*)(ws + 22 * MB);  // 8 MB [NTOK][D]
  short* qkv    = (short*)(ws + 30 * MB);  // 24 MB [NTOK][3072]
  short* m1     = (short*)(ws + 22 * MB);  // 32 MB (aliases xn+qkv after attn)
  short* Kp     = (short*)(ws + 54 * MB);  // 8 MB packed K fragments
  short* Vp     = (short*)(ws + 62 * MB);  // 8 MB packed V fragments
  short* hb     = (short*)(ws + 70 * MB);  // 8 MB [NTOK][D]
  float* parts  = (float*)(ws + 54 * MB);  // 64 MB (aliases Kp/Vp/hb after mlp1)
  float* att    = (float*)d_out;           // att lives in d_out

  cvt_kernel<<<1024, 256, 0, stream>>>(Wq, wqkv_b, 262144);
  cvt_kernel<<<1024, 256, 0, stream>>>(Wk, wqkv_b + 1048576, 262144);
  cvt_kernel<<<1024, 256, 0, stream>>>(Wv, wqkv_b + 2097152, 262144);
  cvt_kernel<<<4096, 256, 0, stream>>>(W1, w1_b, 1048576);
  cvt_kernel<<<4096, 256, 0, stream>>>(W2, w2_b, 1048576);

  ln_kernel<<<NTOK, 256, 0, stream>>>(x, g1, b1, xn);

  gemm8<0><<<dim3(12, 16), 512, 0, stream>>>(xn, wqkv_b, qkv, QKLD, DMODEL, DMODEL,
                                             DMODEL, 0);
  pack_k<<<dim3(64, 32), 256, 0, stream>>>(qkv, Kp);
  pack_v<<<dim3(32, 32), 256, 0, stream>>>(qkv, Vp);

  attn_kernel<<<2048, 64, 0, stream>>>(qkv, Kp, Vp, xn, att);

  ln_kernel<<<NTOK, 256, 0, stream>>>(att, g2, b2, hb);

  gemm8<1><<<dim3(16, 16), 512, 0, stream>>>(hb, w1_b, m1, FFDIM, DMODEL, DMODEL,
                                             DMODEL, 0);
  gemm8<2><<<dim3(4, 16, 4), 512, 0, stream>>>(m1, w2_b, parts, DMODEL, FFDIM, FFDIM,
                                               1024, (long)NTOK * DMODEL);
  combine_kernel<<<4096, 256, 0, stream>>>(parts, (float*)d_out, 1048576);
}